// Round 15
// baseline (343.742 us; speedup 1.0000x reference)
//
#include <hip/hip_runtime.h>
#include <hip/hip_fp16.h>
#include <math.h>

// Problem constants (fixed by the reference)
constexpr int   N   = 50000;
constexpr int   E   = 600000;
constexpr int   FIN = 128;
constexpr int   H   = 64;
constexpr int   C   = 40;
constexpr int   K   = 10;
constexpr float CK  = (1.0f - 0.1f) / 10.0f;  // (1-alpha)/K
constexpr float AL  = 0.1f;                   // alpha

typedef float v2f __attribute__((ext_vector_type(2)));
typedef unsigned v4u __attribute__((ext_vector_type(4)));   // native vec for nontemporal builtins

// pack 4 fp32 -> 4 fp8 e4m3 (HW RNE, OCP on gfx950)
__device__ __forceinline__ unsigned pack_fp8x4(float f0, float f1, float f2, float f3) {
    unsigned r = __builtin_amdgcn_cvt_pk_fp8_f32(f0, f1, 0u, false);
    r = __builtin_amdgcn_cvt_pk_fp8_f32(f2, f3, r, true);
    return r;
}

// 4-byte edge record: low 16 = col (u16, N<=65535), high 16 = fp16 weight
__device__ __forceinline__ float ep_w(unsigned v) {
    return __half2float(__ushort_as_half((unsigned short)(v >> 16)));
}
__device__ __forceinline__ unsigned ep_pack(int c, float w) {
    return (unsigned)(unsigned short)c |
           ((unsigned)__half_as_ushort(__float2half_rn(w)) << 16);
}

// ---------------------------------------------------------------------------
// y0 = x @ W1   (N x 128) @ (128 x 64)
// 64 nodes/block, 256 threads; W1 + padded x rows in LDS; 4x4 register tile.
// ---------------------------------------------------------------------------
constexpr int G1N  = 64;
constexpr int XPAD = 132;
__global__ __launch_bounds__(256, 2) void k_gemm1(const float* __restrict__ x,
                                                  const float* __restrict__ W1,
                                                  float* __restrict__ y0,
                                                  unsigned char* __restrict__ y0f8) {
    __shared__ float ws[FIN * H];
    __shared__ float xs[G1N * XPAD];
    const float4* W14 = (const float4*)W1;
    const float4* x4  = (const float4*)x;
    int t = threadIdx.x;
    int node0 = blockIdx.x * G1N;
    for (int i = t; i < FIN * H / 4; i += 256) ((float4*)ws)[i] = W14[i];
    for (int p = 0; p < 8; ++p) {
        int idx = p * 256 + t;
        int n   = idx >> 5;
        int kk  = idx & 31;
        int node = node0 + n;
        float4 v = (node < N) ? x4[(size_t)node * (FIN / 4) + kk]
                              : make_float4(0.f, 0.f, 0.f, 0.f);
        *(float4*)(xs + n * XPAD + kk * 4) = v;
    }
    __syncthreads();
    int nb = (t >> 4) * 4;
    int cb = (t & 15) * 4;
    float a00=0,a01=0,a02=0,a03=0, a10=0,a11=0,a12=0,a13=0;
    float a20=0,a21=0,a22=0,a23=0, a30=0,a31=0,a32=0,a33=0;
#pragma unroll 8
    for (int k = 0; k < FIN; ++k) {
        float4 wv = *(const float4*)(ws + k * H + cb);
        float x0 = xs[(nb + 0) * XPAD + k];
        float x1 = xs[(nb + 1) * XPAD + k];
        float x2 = xs[(nb + 2) * XPAD + k];
        float x3 = xs[(nb + 3) * XPAD + k];
        a00 = fmaf(x0, wv.x, a00); a01 = fmaf(x0, wv.y, a01);
        a02 = fmaf(x0, wv.z, a02); a03 = fmaf(x0, wv.w, a03);
        a10 = fmaf(x1, wv.x, a10); a11 = fmaf(x1, wv.y, a11);
        a12 = fmaf(x1, wv.z, a12); a13 = fmaf(x1, wv.w, a13);
        a20 = fmaf(x2, wv.x, a20); a21 = fmaf(x2, wv.y, a21);
        a22 = fmaf(x2, wv.z, a22); a23 = fmaf(x2, wv.w, a23);
        a30 = fmaf(x3, wv.x, a30); a31 = fmaf(x3, wv.y, a31);
        a32 = fmaf(x3, wv.z, a32); a33 = fmaf(x3, wv.w, a33);
    }
    float4 rows[4] = {make_float4(a00,a01,a02,a03), make_float4(a10,a11,a12,a13),
                      make_float4(a20,a21,a22,a23), make_float4(a30,a31,a32,a33)};
#pragma unroll
    for (int i = 0; i < 4; ++i) {
        int node = node0 + nb + i;
        if (node >= N) break;
        float4 r = rows[i];
        *(float4*)(y0 + (size_t)node * H + cb) = r;
        *(unsigned*)(y0f8 + (size_t)node * H + cb) = pack_fp8x4(r.x, r.y, r.z, r.w);
    }
}

// ---------------------------------------------------------------------------
// Per-row edge count, 8-way privatized (blockIdx&7 -> XCD-local atomics)
// ---------------------------------------------------------------------------
__global__ void k_count(const int* __restrict__ row, int* __restrict__ cnt8) {
    int e = blockIdx.x * blockDim.x + threadIdx.x;
    if (e >= E) return;
    atomicAdd(&cnt8[(size_t)(blockIdx.x & 7) * N + row[e]], 1);
}

// ---------------------------------------------------------------------------
// Two-level exclusive scan of summed cnt8 -> row_ptr[]
// ---------------------------------------------------------------------------
__global__ __launch_bounds__(1024) void k_scan_blocks(const int* __restrict__ cnt8,
                                                      int* __restrict__ row_ptr,
                                                      int* __restrict__ bsum) {
    __shared__ int s[1024];
    int gid = blockIdx.x * 1024 + threadIdx.x;
    int v = 0;
    if (gid < N) {
#pragma unroll
        for (int c = 0; c < 8; ++c) v += cnt8[(size_t)c * N + gid];
    }
    s[threadIdx.x] = v;
    __syncthreads();
    for (int off = 1; off < 1024; off <<= 1) {
        int t = (threadIdx.x >= off) ? s[threadIdx.x - off] : 0;
        __syncthreads();
        s[threadIdx.x] += t;
        __syncthreads();
    }
    if (gid < N) row_ptr[gid] = s[threadIdx.x] - v;  // exclusive
    if (threadIdx.x == 1023) bsum[blockIdx.x] = s[1023];
}

__global__ void k_scan_sums(const int* __restrict__ bsum, int* __restrict__ boff, int nb) {
    int lane = threadIdx.x;
    int orig = (lane < nb) ? bsum[lane] : 0;
    int v = orig;
    for (int off = 1; off < 64; off <<= 1) {
        int t = __shfl_up(v, off, 64);
        if (lane >= off) v += t;
    }
    if (lane < nb) boff[lane] = v - orig;
}

// Add block offsets AND convert cnt8 copies into per-copy scatter bases
__global__ __launch_bounds__(1024) void k_addoff(int* __restrict__ row_ptr,
                                                 const int* __restrict__ boff,
                                                 int* __restrict__ cnt8) {
    int gid = blockIdx.x * 1024 + threadIdx.x;
    if (gid < N) {
        int rp = row_ptr[gid] + boff[blockIdx.x];
        row_ptr[gid] = rp;
        int off = rp;
#pragma unroll
        for (int c = 0; c < 8; ++c) {
            int t = cnt8[(size_t)c * N + gid];
            cnt8[(size_t)c * N + gid] = off;
            off += t;
        }
    }
    if (gid == 0) row_ptr[N] = E;
}

// ---------------------------------------------------------------------------
// Scatter edges into CSR (4 B records); atomics within XCD-private copy.
// Same edge->block mapping as k_count (256 edges/block).
// ---------------------------------------------------------------------------
__global__ void k_scatter(const int* __restrict__ row, const int* __restrict__ col,
                          const float* __restrict__ w,
                          int* __restrict__ off8, unsigned* __restrict__ ep) {
    int e = blockIdx.x * blockDim.x + threadIdx.x;
    if (e >= E) return;
    int r = row[e];
    int p = atomicAdd(&off8[(size_t)(blockIdx.x & 7) * N + r], 1);
    ep[p] = ep_pack(col[e], w[e]);
}

// ---------------------------------------------------------------------------
// Weighted degree from CSR rows + dinv/dinv2
// ---------------------------------------------------------------------------
__global__ void k_deg_dinv(const unsigned* __restrict__ ep, const int* __restrict__ row_ptr,
                           float* __restrict__ dinv, float* __restrict__ dinv2) {
    int i = blockIdx.x * blockDim.x + threadIdx.x;
    if (i >= N) return;
    float d = 1.0f;   // self-loop weight
    int e0 = row_ptr[i], e1 = row_ptr[i + 1];
    for (int j = e0; j < e1; ++j) d += ep_w(ep[j]);
    float di = rsqrtf(d);
    dinv[i]  = di;
    dinv2[i] = di * di;
}

// ---------------------------------------------------------------------------
// Normalize edge weights in place: w <- dinv[r]*w*dinv[c]
// ---------------------------------------------------------------------------
__global__ __launch_bounds__(256) void k_norm(unsigned* __restrict__ ep,
                                              const int* __restrict__ row_ptr,
                                              const float* __restrict__ dinv) {
    int node = blockIdx.x * 32 + (threadIdx.x >> 3);
    if (node >= N) return;
    int l = threadIdx.x & 7;
    float dr = dinv[node];
    int e0 = row_ptr[node], e1 = row_ptr[node + 1];
    for (int j = e0 + l; j < e1; j += 8) {
        unsigned v = ep[j];
        int c = v & 0xFFFFu;
        ep[j] = ep_pack(c, ep_w(v) * dr * dinv[c]);
    }
}

// ---------------------------------------------------------------------------
// One propagation hop, fp8 h storage (64 B row), 4 B edge records.
// 8 nodes/wave, 2 edges in flight, 32 nodes/block. acc fp16 in global with
// NONTEMPORAL RMW (streamed once/hop; keep L2 for the h gather set).
// FINAL fuses the MLP epilogue.
// ---------------------------------------------------------------------------
constexpr int HSP = 68;
template <bool WRITE_H, bool ACC_INIT, bool FINAL>
__global__ __launch_bounds__(256) void k_prop(const uint2* __restrict__ hin,   // N x 8 (fp8x8)
                                              uint2* __restrict__ hout,
                                              __half* __restrict__ acch,       // N x H fp16
                                              const float* __restrict__ dinv2,
                                              const int* __restrict__ row_ptr,
                                              const unsigned* __restrict__ ep,
                                              const float4* __restrict__ y04,
                                              const float* __restrict__ b1,
                                              const float* __restrict__ W2,
                                              const float* __restrict__ b2,
                                              float* __restrict__ out) {
    extern __shared__ float smem[];          // FINAL only: w2s | hs | b2s | b1s
    float* w2s = smem;
    float* hs  = smem + H * C;
    float* b2s = hs + 32 * HSP;
    float* b1s = b2s + C;
    int t = threadIdx.x;
    if (FINAL) {
        for (int i = t; i < H * C; i += 256) w2s[i] = W2[i];
        if (t < C) b2s[t] = b2[t];
        if (t < H) b1s[t] = b1[t];
        __syncthreads();
    }
    int lane = t & 63;
    int nib  = (t >> 6) * 8 + (lane >> 3);   // node-in-block 0..31
    int l    = lane & 7;                     // feature octet
    int node = blockIdx.x * 32 + nib;
    bool nv  = node < N;
    int nodec = nv ? node : N - 1;
    int start = row_ptr[nodec];
    int deg   = nv ? (row_ptr[nodec + 1] - start) : 0;
    int md = deg;
#pragma unroll
    for (int off = 8; off <= 32; off <<= 1) md = max(md, __shfl_xor(md, off, 64));
    float s[8];
#pragma unroll
    for (int i = 0; i < 8; ++i) s[i] = 0.f;
    auto accum = [&](uint2 v, float w) {
        v2f p0 = __builtin_amdgcn_cvt_pk_f32_fp8(v.x, false);
        v2f p1 = __builtin_amdgcn_cvt_pk_f32_fp8(v.x, true);
        v2f p2 = __builtin_amdgcn_cvt_pk_f32_fp8(v.y, false);
        v2f p3 = __builtin_amdgcn_cvt_pk_f32_fp8(v.y, true);
        s[0] = fmaf(w, p0.x, s[0]); s[1] = fmaf(w, p0.y, s[1]);
        s[2] = fmaf(w, p1.x, s[2]); s[3] = fmaf(w, p1.y, s[3]);
        s[4] = fmaf(w, p2.x, s[4]); s[5] = fmaf(w, p2.y, s[5]);
        s[6] = fmaf(w, p3.x, s[6]); s[7] = fmaf(w, p3.y, s[7]);
    };
    for (int j = 0; j < md; j += 2) {
        bool a0 = j < deg, a1 = j + 1 < deg;
        unsigned e0 = ep[a0 ? start + j     : 0];
        unsigned e1 = ep[a1 ? start + j + 1 : 0];
        uint2 v0 = hin[(size_t)(e0 & 0xFFFFu) * 8 + l];
        uint2 v1 = hin[(size_t)(e1 & 0xFFFFu) * 8 + l];
        float w0 = a0 ? ep_w(e0) : 0.0f;
        float w1 = a1 ? ep_w(e1) : 0.0f;
        accum(v0, w0);
        accum(v1, w1);
    }
    if (nv) {
        size_t base = (size_t)nodec * 8 + l;
        accum(hin[base], dinv2[nodec]);      // self-loop term
        if (WRITE_H) {
            uint2 o;
            o.x = pack_fp8x4(s[0], s[1], s[2], s[3]);
            o.y = pack_fp8x4(s[4], s[5], s[6], s[7]);
            hout[base] = o;
        }
        v4u* ap = (v4u*)(acch + (size_t)nodec * H + l * 8);
        if (FINAL) {
            v4u old = __builtin_nontemporal_load(ap);
#pragma unroll
            for (int d = 0; d < 4; ++d) {
                unsigned ud = old[d];
                float2 f = __half22float2(*(__half2*)&ud);
                s[2*d+0] += f.x; s[2*d+1] += f.y;
            }
            float4 ya = y04[(size_t)nodec * (H / 4) + 2 * l];
            float4 yb = y04[(size_t)nodec * (H / 4) + 2 * l + 1];
            const float* bp = b1s + l * 8;
            float* hp = hs + nib * HSP + l * 8;
            hp[0] = fmaxf(fmaf(CK, s[0], fmaf(AL, ya.x, bp[0])), 0.f);
            hp[1] = fmaxf(fmaf(CK, s[1], fmaf(AL, ya.y, bp[1])), 0.f);
            hp[2] = fmaxf(fmaf(CK, s[2], fmaf(AL, ya.z, bp[2])), 0.f);
            hp[3] = fmaxf(fmaf(CK, s[3], fmaf(AL, ya.w, bp[3])), 0.f);
            hp[4] = fmaxf(fmaf(CK, s[4], fmaf(AL, yb.x, bp[4])), 0.f);
            hp[5] = fmaxf(fmaf(CK, s[5], fmaf(AL, yb.y, bp[5])), 0.f);
            hp[6] = fmaxf(fmaf(CK, s[6], fmaf(AL, yb.z, bp[6])), 0.f);
            hp[7] = fmaxf(fmaf(CK, s[7], fmaf(AL, yb.w, bp[7])), 0.f);
        } else {
            if (!ACC_INIT) {
                v4u old = __builtin_nontemporal_load(ap);
#pragma unroll
                for (int d = 0; d < 4; ++d) {
                    unsigned ud = old[d];
                    float2 f = __half22float2(*(__half2*)&ud);
                    s[2*d+0] += f.x; s[2*d+1] += f.y;
                }
            }
            v4u nvp;
#pragma unroll
            for (int d = 0; d < 4; ++d) {
                __half2 h = __floats2half2_rn(s[2*d+0], s[2*d+1]);
                nvp[d] = *(unsigned*)&h;
            }
            __builtin_nontemporal_store(nvp, ap);
        }
    }
    if (FINAL) {
        __syncthreads();
        int node0 = blockIdx.x * 32;
        for (int o = t; o < 32 * C; o += 256) {
            int nl = o / C, c = o % C;
            int n2 = node0 + nl;
            if (n2 >= N) continue;
            float v = b2s[c];
            const float* hr = &hs[nl * HSP];
#pragma unroll
            for (int k = 0; k < H; ++k) v = fmaf(hr[k], w2s[k * C + c], v);
            out[n2 * C + c] = v;
        }
    }
}

// ---------------------------------------------------------------------------
extern "C" void kernel_launch(void* const* d_in, const int* in_sizes, int n_in,
                              void* d_out, int out_size, void* d_ws, size_t ws_size,
                              hipStream_t stream) {
    const float* x  = (const float*)d_in[0];
    const int*   ei = (const int*)d_in[1];
    const float* ew = (const float*)d_in[2];
    const float* W1 = (const float*)d_in[3];
    const float* b1 = (const float*)d_in[4];
    const float* W2 = (const float*)d_in[5];
    const float* b2 = (const float*)d_in[6];
    float* out = (float*)d_out;

    const int* row = ei;
    const int* col = ei + E;

    char* ws = (char*)d_ws;
    size_t off = 0;
    auto alloc = [&](size_t bytes) -> char* {
        char* p = ws + off;
        off = (off + bytes + 1023) & ~(size_t)1023;
        return p;
    };
    float*         y0   = (float*)alloc((size_t)N * H * 4);
    unsigned char* y0f8 = (unsigned char*)alloc((size_t)N * H);
    unsigned char* ha   = (unsigned char*)alloc((size_t)N * H);
    unsigned char* hb   = (unsigned char*)alloc((size_t)N * H);
    __half*        acch = (__half*)alloc((size_t)N * H * 2);
    int*      cnt8   = (int*)     alloc((size_t)8 * N * 4);  // zeroed
    float*    dinv   = (float*)   alloc((size_t)N * 4);
    float*    dinv2  = (float*)   alloc((size_t)N * 4);
    int*      row_ptr= (int*)     alloc((size_t)(N + 1) * 4);
    int*      bsum   = (int*)     alloc(64 * 4);
    int*      boff   = (int*)     alloc(64 * 4);
    unsigned* ep     = (unsigned*)alloc((size_t)E * 4);

    (void)hipMemsetAsync(cnt8, 0, (size_t)8 * N * 4, stream);

    // 1) y0 = x @ W1 (fp32 + fp8)
    k_gemm1<<<(N + G1N - 1) / G1N, 256, 0, stream>>>(x, W1, y0, y0f8);

    // 2) per-row edge counts (XCD-privatized)
    k_count<<<(E + 255) / 256, 256, 0, stream>>>(row, cnt8);

    // 3) scan -> row_ptr; per-copy scatter bases (fused)
    constexpr int NB = (N + 1023) / 1024;  // 49
    k_scan_blocks<<<NB, 1024, 0, stream>>>(cnt8, row_ptr, bsum);
    k_scan_sums<<<1, 64, 0, stream>>>(bsum, boff, NB);
    k_addoff<<<NB, 1024, 0, stream>>>(row_ptr, boff, cnt8);

    // 4) scatter (4 B records), weighted degree + dinv, normalize
    k_scatter<<<(E + 255) / 256, 256, 0, stream>>>(row, col, ew, cnt8, ep);
    k_deg_dinv<<<(N + 255) / 256, 256, 0, stream>>>(ep, row_ptr, dinv, dinv2);
    k_norm<<<(N + 31) / 32, 256, 0, stream>>>(ep, row_ptr, dinv);

    // 5) K hops; hop 0 inits acc, hop K-1 fuses the MLP epilogue
    const uint2* hin = (const uint2*)y0f8;
    uint2* bufs[2] = {(uint2*)ha, (uint2*)hb};
    const float4* y04 = (const float4*)y0;
    int grid = (N + 31) / 32;
    size_t smemF = (size_t)(H * C + 32 * HSP + C + H) * 4;
    for (int hop = 0; hop < K; ++hop) {
        uint2* hout = bufs[hop & 1];
        if (hop == 0)
            k_prop<true, true, false><<<grid, 256, 0, stream>>>(hin, hout, acch, dinv2,
                row_ptr, ep, y04, b1, W2, b2, out);
        else if (hop == K - 1)
            k_prop<false, false, true><<<grid, 256, smemF, stream>>>(hin, hout, acch, dinv2,
                row_ptr, ep, y04, b1, W2, b2, out);
        else
            k_prop<true, false, false><<<grid, 256, 0, stream>>>(hin, hout, acch, dinv2,
                row_ptr, ep, y04, b1, W2, b2, out);
        hin = hout;
    }
}

// Round 16
// 333.378 us; speedup vs baseline: 1.0311x; 1.0311x over previous
//
#include <hip/hip_runtime.h>
#include <hip/hip_fp16.h>
#include <math.h>

// Problem constants (fixed by the reference)
constexpr int   N   = 50000;
constexpr int   E   = 600000;
constexpr int   FIN = 128;
constexpr int   H   = 64;
constexpr int   C   = 40;
constexpr int   K   = 10;
constexpr float CK  = (1.0f - 0.1f) / 10.0f;  // (1-alpha)/K
constexpr float AL  = 0.1f;                   // alpha

typedef float v2f __attribute__((ext_vector_type(2)));

// pack 4 fp32 -> 4 fp8 e4m3 (HW RNE, OCP on gfx950)
__device__ __forceinline__ unsigned pack_fp8x4(float f0, float f1, float f2, float f3) {
    unsigned r = __builtin_amdgcn_cvt_pk_fp8_f32(f0, f1, 0u, false);
    r = __builtin_amdgcn_cvt_pk_fp8_f32(f2, f3, r, true);
    return r;
}

// 4-byte edge record: low 16 = col (u16, N<=65535), high 16 = fp16 weight
__device__ __forceinline__ float ep_w(unsigned v) {
    return __half2float(__ushort_as_half((unsigned short)(v >> 16)));
}
__device__ __forceinline__ unsigned ep_pack(int c, float w) {
    return (unsigned)(unsigned short)c |
           ((unsigned)__half_as_ushort(__float2half_rn(w)) << 16);
}

// ---------------------------------------------------------------------------
// y0 = x @ W1   (N x 128) @ (128 x 64)
// 64 nodes/block, 256 threads; W1 + padded x rows in LDS; 4x4 register tile.
// ---------------------------------------------------------------------------
constexpr int G1N  = 64;
constexpr int XPAD = 132;
__global__ __launch_bounds__(256, 2) void k_gemm1(const float* __restrict__ x,
                                                  const float* __restrict__ W1,
                                                  float* __restrict__ y0,
                                                  unsigned char* __restrict__ y0f8) {
    __shared__ float ws[FIN * H];
    __shared__ float xs[G1N * XPAD];
    const float4* W14 = (const float4*)W1;
    const float4* x4  = (const float4*)x;
    int t = threadIdx.x;
    int node0 = blockIdx.x * G1N;
    for (int i = t; i < FIN * H / 4; i += 256) ((float4*)ws)[i] = W14[i];
    for (int p = 0; p < 8; ++p) {
        int idx = p * 256 + t;
        int n   = idx >> 5;
        int kk  = idx & 31;
        int node = node0 + n;
        float4 v = (node < N) ? x4[(size_t)node * (FIN / 4) + kk]
                              : make_float4(0.f, 0.f, 0.f, 0.f);
        *(float4*)(xs + n * XPAD + kk * 4) = v;
    }
    __syncthreads();
    int nb = (t >> 4) * 4;
    int cb = (t & 15) * 4;
    float a00=0,a01=0,a02=0,a03=0, a10=0,a11=0,a12=0,a13=0;
    float a20=0,a21=0,a22=0,a23=0, a30=0,a31=0,a32=0,a33=0;
#pragma unroll 8
    for (int k = 0; k < FIN; ++k) {
        float4 wv = *(const float4*)(ws + k * H + cb);
        float x0 = xs[(nb + 0) * XPAD + k];
        float x1 = xs[(nb + 1) * XPAD + k];
        float x2 = xs[(nb + 2) * XPAD + k];
        float x3 = xs[(nb + 3) * XPAD + k];
        a00 = fmaf(x0, wv.x, a00); a01 = fmaf(x0, wv.y, a01);
        a02 = fmaf(x0, wv.z, a02); a03 = fmaf(x0, wv.w, a03);
        a10 = fmaf(x1, wv.x, a10); a11 = fmaf(x1, wv.y, a11);
        a12 = fmaf(x1, wv.z, a12); a13 = fmaf(x1, wv.w, a13);
        a20 = fmaf(x2, wv.x, a20); a21 = fmaf(x2, wv.y, a21);
        a22 = fmaf(x2, wv.z, a22); a23 = fmaf(x2, wv.w, a23);
        a30 = fmaf(x3, wv.x, a30); a31 = fmaf(x3, wv.y, a31);
        a32 = fmaf(x3, wv.z, a32); a33 = fmaf(x3, wv.w, a33);
    }
    float4 rows[4] = {make_float4(a00,a01,a02,a03), make_float4(a10,a11,a12,a13),
                      make_float4(a20,a21,a22,a23), make_float4(a30,a31,a32,a33)};
#pragma unroll
    for (int i = 0; i < 4; ++i) {
        int node = node0 + nb + i;
        if (node >= N) break;
        float4 r = rows[i];
        *(float4*)(y0 + (size_t)node * H + cb) = r;
        *(unsigned*)(y0f8 + (size_t)node * H + cb) = pack_fp8x4(r.x, r.y, r.z, r.w);
    }
}

// ---------------------------------------------------------------------------
// Per-row edge count, 8-way privatized (blockIdx&7 -> XCD-local atomics)
// ---------------------------------------------------------------------------
__global__ void k_count(const int* __restrict__ row, int* __restrict__ cnt8) {
    int e = blockIdx.x * blockDim.x + threadIdx.x;
    if (e >= E) return;
    atomicAdd(&cnt8[(size_t)(blockIdx.x & 7) * N + row[e]], 1);
}

// ---------------------------------------------------------------------------
// Two-level exclusive scan of summed cnt8 -> row_ptr[]
// ---------------------------------------------------------------------------
__global__ __launch_bounds__(1024) void k_scan_blocks(const int* __restrict__ cnt8,
                                                      int* __restrict__ row_ptr,
                                                      int* __restrict__ bsum) {
    __shared__ int s[1024];
    int gid = blockIdx.x * 1024 + threadIdx.x;
    int v = 0;
    if (gid < N) {
#pragma unroll
        for (int c = 0; c < 8; ++c) v += cnt8[(size_t)c * N + gid];
    }
    s[threadIdx.x] = v;
    __syncthreads();
    for (int off = 1; off < 1024; off <<= 1) {
        int t = (threadIdx.x >= off) ? s[threadIdx.x - off] : 0;
        __syncthreads();
        s[threadIdx.x] += t;
        __syncthreads();
    }
    if (gid < N) row_ptr[gid] = s[threadIdx.x] - v;  // exclusive
    if (threadIdx.x == 1023) bsum[blockIdx.x] = s[1023];
}

__global__ void k_scan_sums(const int* __restrict__ bsum, int* __restrict__ boff, int nb) {
    int lane = threadIdx.x;
    int orig = (lane < nb) ? bsum[lane] : 0;
    int v = orig;
    for (int off = 1; off < 64; off <<= 1) {
        int t = __shfl_up(v, off, 64);
        if (lane >= off) v += t;
    }
    if (lane < nb) boff[lane] = v - orig;
}

// Add block offsets AND convert cnt8 copies into per-copy scatter bases
__global__ __launch_bounds__(1024) void k_addoff(int* __restrict__ row_ptr,
                                                 const int* __restrict__ boff,
                                                 int* __restrict__ cnt8) {
    int gid = blockIdx.x * 1024 + threadIdx.x;
    if (gid < N) {
        int rp = row_ptr[gid] + boff[blockIdx.x];
        row_ptr[gid] = rp;
        int off = rp;
#pragma unroll
        for (int c = 0; c < 8; ++c) {
            int t = cnt8[(size_t)c * N + gid];
            cnt8[(size_t)c * N + gid] = off;
            off += t;
        }
    }
    if (gid == 0) row_ptr[N] = E;
}

// ---------------------------------------------------------------------------
// Scatter edges into CSR (4 B records); atomics within XCD-private copy.
// ---------------------------------------------------------------------------
__global__ void k_scatter(const int* __restrict__ row, const int* __restrict__ col,
                          const float* __restrict__ w,
                          int* __restrict__ off8, unsigned* __restrict__ ep) {
    int e = blockIdx.x * blockDim.x + threadIdx.x;
    if (e >= E) return;
    int r = row[e];
    int p = atomicAdd(&off8[(size_t)(blockIdx.x & 7) * N + r], 1);
    ep[p] = ep_pack(col[e], w[e]);
}

// ---------------------------------------------------------------------------
// Weighted degree from CSR rows + dinv/dinv2
// ---------------------------------------------------------------------------
__global__ void k_deg_dinv(const unsigned* __restrict__ ep, const int* __restrict__ row_ptr,
                           float* __restrict__ dinv, float* __restrict__ dinv2) {
    int i = blockIdx.x * blockDim.x + threadIdx.x;
    if (i >= N) return;
    float d = 1.0f;   // self-loop weight
    int e0 = row_ptr[i], e1 = row_ptr[i + 1];
    for (int j = e0; j < e1; ++j) d += ep_w(ep[j]);
    float di = rsqrtf(d);
    dinv[i]  = di;
    dinv2[i] = di * di;
}

// ---------------------------------------------------------------------------
// Normalize edge weights in place: w <- dinv[r]*w*dinv[c]
// ---------------------------------------------------------------------------
__global__ __launch_bounds__(256) void k_norm(unsigned* __restrict__ ep,
                                              const int* __restrict__ row_ptr,
                                              const float* __restrict__ dinv) {
    int node = blockIdx.x * 32 + (threadIdx.x >> 3);
    if (node >= N) return;
    int l = threadIdx.x & 7;
    float dr = dinv[node];
    int e0 = row_ptr[node], e1 = row_ptr[node + 1];
    for (int j = e0 + l; j < e1; j += 8) {
        unsigned v = ep[j];
        int c = v & 0xFFFFu;
        ep[j] = ep_pack(c, ep_w(v) * dr * dinv[c]);
    }
}

// ---------------------------------------------------------------------------
// One propagation hop, fp8 h storage (64 B row), 4 B edge records.
// 8 nodes/wave (lane = node-sub x feature-octet), 2 edges in flight.
// 32 nodes/block. acc fp16 in global (plain RMW — L3 caches it across hops).
// FINAL fuses the MLP epilogue.
// ---------------------------------------------------------------------------
constexpr int HSP = 68;
template <bool WRITE_H, bool ACC_INIT, bool FINAL>
__global__ __launch_bounds__(256) void k_prop(const uint2* __restrict__ hin,   // N x 8 (fp8x8)
                                              uint2* __restrict__ hout,
                                              __half* __restrict__ acch,       // N x H fp16
                                              const float* __restrict__ dinv2,
                                              const int* __restrict__ row_ptr,
                                              const unsigned* __restrict__ ep,
                                              const float4* __restrict__ y04,
                                              const float* __restrict__ b1,
                                              const float* __restrict__ W2,
                                              const float* __restrict__ b2,
                                              float* __restrict__ out) {
    extern __shared__ float smem[];          // FINAL only: w2s | hs | b2s | b1s
    float* w2s = smem;
    float* hs  = smem + H * C;
    float* b2s = hs + 32 * HSP;
    float* b1s = b2s + C;
    int t = threadIdx.x;
    if (FINAL) {
        for (int i = t; i < H * C; i += 256) w2s[i] = W2[i];
        if (t < C) b2s[t] = b2[t];
        if (t < H) b1s[t] = b1[t];
        __syncthreads();
    }
    int lane = t & 63;
    int nib  = (t >> 6) * 8 + (lane >> 3);   // node-in-block 0..31
    int l    = lane & 7;                     // feature octet
    int node = blockIdx.x * 32 + nib;
    bool nv  = node < N;
    int nodec = nv ? node : N - 1;
    int start = row_ptr[nodec];
    int deg   = nv ? (row_ptr[nodec + 1] - start) : 0;
    int md = deg;
#pragma unroll
    for (int off = 8; off <= 32; off <<= 1) md = max(md, __shfl_xor(md, off, 64));
    float s[8];
#pragma unroll
    for (int i = 0; i < 8; ++i) s[i] = 0.f;
    auto accum = [&](uint2 v, float w) {
        v2f p0 = __builtin_amdgcn_cvt_pk_f32_fp8(v.x, false);
        v2f p1 = __builtin_amdgcn_cvt_pk_f32_fp8(v.x, true);
        v2f p2 = __builtin_amdgcn_cvt_pk_f32_fp8(v.y, false);
        v2f p3 = __builtin_amdgcn_cvt_pk_f32_fp8(v.y, true);
        s[0] = fmaf(w, p0.x, s[0]); s[1] = fmaf(w, p0.y, s[1]);
        s[2] = fmaf(w, p1.x, s[2]); s[3] = fmaf(w, p1.y, s[3]);
        s[4] = fmaf(w, p2.x, s[4]); s[5] = fmaf(w, p2.y, s[5]);
        s[6] = fmaf(w, p3.x, s[6]); s[7] = fmaf(w, p3.y, s[7]);
    };
    for (int j = 0; j < md; j += 2) {
        bool a0 = j < deg, a1 = j + 1 < deg;
        unsigned e0 = ep[a0 ? start + j     : 0];
        unsigned e1 = ep[a1 ? start + j + 1 : 0];
        uint2 v0 = hin[(size_t)(e0 & 0xFFFFu) * 8 + l];
        uint2 v1 = hin[(size_t)(e1 & 0xFFFFu) * 8 + l];
        float w0 = a0 ? ep_w(e0) : 0.0f;
        float w1 = a1 ? ep_w(e1) : 0.0f;
        accum(v0, w0);
        accum(v1, w1);
    }
    if (nv) {
        size_t base = (size_t)nodec * 8 + l;
        accum(hin[base], dinv2[nodec]);      // self-loop term
        if (WRITE_H) {
            uint2 o;
            o.x = pack_fp8x4(s[0], s[1], s[2], s[3]);
            o.y = pack_fp8x4(s[4], s[5], s[6], s[7]);
            hout[base] = o;
        }
        uint4* ap = (uint4*)(acch + (size_t)nodec * H + l * 8);
        if (FINAL) {
            uint4 old = *ap;
            const unsigned* u = (const unsigned*)&old;
#pragma unroll
            for (int d = 0; d < 4; ++d) {
                float2 f = __half22float2(*(__half2*)&u[d]);
                s[2*d+0] += f.x; s[2*d+1] += f.y;
            }
            float4 ya = y04[(size_t)nodec * (H / 4) + 2 * l];
            float4 yb = y04[(size_t)nodec * (H / 4) + 2 * l + 1];
            const float* bp = b1s + l * 8;
            float* hp = hs + nib * HSP + l * 8;
            hp[0] = fmaxf(fmaf(CK, s[0], fmaf(AL, ya.x, bp[0])), 0.f);
            hp[1] = fmaxf(fmaf(CK, s[1], fmaf(AL, ya.y, bp[1])), 0.f);
            hp[2] = fmaxf(fmaf(CK, s[2], fmaf(AL, ya.z, bp[2])), 0.f);
            hp[3] = fmaxf(fmaf(CK, s[3], fmaf(AL, ya.w, bp[3])), 0.f);
            hp[4] = fmaxf(fmaf(CK, s[4], fmaf(AL, yb.x, bp[4])), 0.f);
            hp[5] = fmaxf(fmaf(CK, s[5], fmaf(AL, yb.y, bp[5])), 0.f);
            hp[6] = fmaxf(fmaf(CK, s[6], fmaf(AL, yb.z, bp[6])), 0.f);
            hp[7] = fmaxf(fmaf(CK, s[7], fmaf(AL, yb.w, bp[7])), 0.f);
        } else {
            if (!ACC_INIT) {
                uint4 old = *ap;
                const unsigned* u = (const unsigned*)&old;
#pragma unroll
                for (int d = 0; d < 4; ++d) {
                    float2 f = __half22float2(*(__half2*)&u[d]);
                    s[2*d+0] += f.x; s[2*d+1] += f.y;
                }
            }
            uint4 nvp;
            unsigned* u = (unsigned*)&nvp;
#pragma unroll
            for (int d = 0; d < 4; ++d) {
                __half2 h = __floats2half2_rn(s[2*d+0], s[2*d+1]);
                u[d] = *(unsigned*)&h;
            }
            *ap = nvp;
        }
    }
    if (FINAL) {
        __syncthreads();
        int node0 = blockIdx.x * 32;
        for (int o = t; o < 32 * C; o += 256) {
            int nl = o / C, c = o % C;
            int n2 = node0 + nl;
            if (n2 >= N) continue;
            float v = b2s[c];
            const float* hr = &hs[nl * HSP];
#pragma unroll
            for (int k = 0; k < H; ++k) v = fmaf(hr[k], w2s[k * C + c], v);
            out[n2 * C + c] = v;
        }
    }
}

// ---------------------------------------------------------------------------
extern "C" void kernel_launch(void* const* d_in, const int* in_sizes, int n_in,
                              void* d_out, int out_size, void* d_ws, size_t ws_size,
                              hipStream_t stream) {
    const float* x  = (const float*)d_in[0];
    const int*   ei = (const int*)d_in[1];
    const float* ew = (const float*)d_in[2];
    const float* W1 = (const float*)d_in[3];
    const float* b1 = (const float*)d_in[4];
    const float* W2 = (const float*)d_in[5];
    const float* b2 = (const float*)d_in[6];
    float* out = (float*)d_out;

    const int* row = ei;
    const int* col = ei + E;

    char* ws = (char*)d_ws;
    size_t off = 0;
    auto alloc = [&](size_t bytes) -> char* {
        char* p = ws + off;
        off = (off + bytes + 1023) & ~(size_t)1023;
        return p;
    };
    float*         y0   = (float*)alloc((size_t)N * H * 4);
    unsigned char* y0f8 = (unsigned char*)alloc((size_t)N * H);
    unsigned char* ha   = (unsigned char*)alloc((size_t)N * H);
    unsigned char* hb   = (unsigned char*)alloc((size_t)N * H);
    __half*        acch = (__half*)alloc((size_t)N * H * 2);
    int*      cnt8   = (int*)     alloc((size_t)8 * N * 4);  // zeroed
    float*    dinv   = (float*)   alloc((size_t)N * 4);
    float*    dinv2  = (float*)   alloc((size_t)N * 4);
    int*      row_ptr= (int*)     alloc((size_t)(N + 1) * 4);
    int*      bsum   = (int*)     alloc(64 * 4);
    int*      boff   = (int*)     alloc(64 * 4);
    unsigned* ep     = (unsigned*)alloc((size_t)E * 4);

    (void)hipMemsetAsync(cnt8, 0, (size_t)8 * N * 4, stream);

    // 1) y0 = x @ W1 (fp32 + fp8)
    k_gemm1<<<(N + G1N - 1) / G1N, 256, 0, stream>>>(x, W1, y0, y0f8);

    // 2) per-row edge counts (XCD-privatized)
    k_count<<<(E + 255) / 256, 256, 0, stream>>>(row, cnt8);

    // 3) scan -> row_ptr; per-copy scatter bases (fused)
    constexpr int NB = (N + 1023) / 1024;  // 49
    k_scan_blocks<<<NB, 1024, 0, stream>>>(cnt8, row_ptr, bsum);
    k_scan_sums<<<1, 64, 0, stream>>>(bsum, boff, NB);
    k_addoff<<<NB, 1024, 0, stream>>>(row_ptr, boff, cnt8);

    // 4) scatter (4 B records), weighted degree + dinv, normalize
    k_scatter<<<(E + 255) / 256, 256, 0, stream>>>(row, col, ew, cnt8, ep);
    k_deg_dinv<<<(N + 255) / 256, 256, 0, stream>>>(ep, row_ptr, dinv, dinv2);
    k_norm<<<(N + 31) / 32, 256, 0, stream>>>(ep, row_ptr, dinv);

    // 5) K hops; hop 0 inits acc, hop K-1 fuses the MLP epilogue
    const uint2* hin = (const uint2*)y0f8;
    uint2* bufs[2] = {(uint2*)ha, (uint2*)hb};
    const float4* y04 = (const float4*)y0;
    int grid = (N + 31) / 32;
    size_t smemF = (size_t)(H * C + 32 * HSP + C + H) * 4;
    for (int hop = 0; hop < K; ++hop) {
        uint2* hout = bufs[hop & 1];
        if (hop == 0)
            k_prop<true, true, false><<<grid, 256, 0, stream>>>(hin, hout, acch, dinv2,
                row_ptr, ep, y04, b1, W2, b2, out);
        else if (hop == K - 1)
            k_prop<false, false, true><<<grid, 256, smemF, stream>>>(hin, hout, acch, dinv2,
                row_ptr, ep, y04, b1, W2, b2, out);
        else
            k_prop<true, false, false><<<grid, 256, 0, stream>>>(hin, hout, acch, dinv2,
                row_ptr, ep, y04, b1, W2, b2, out);
        hin = hout;
    }
}